// Round 10
// baseline (518.651 us; speedup 1.0000x reference)
//
#include <hip/hip_runtime.h>
#include <stdint.h>

#define TL  2048
#define NB  4096
#define INSZ 8
#define HID 10
#define LOG2E 1.4426950408889634f
#define XS (NB * INSZ)            // floats per timestep slab
#define TSTEPS 16                 // timesteps per staged tile (1 KB DMA)
#define NBUF 4
#define NTILES (TL / TSTEPS)      // 128

typedef float v2f __attribute__((ext_vector_type(2)));

__device__ __forceinline__ float rcp_(float x)  { return __builtin_amdgcn_rcpf(x); }
__device__ __forceinline__ float exp2_(float x) { return __builtin_amdgcn_exp2f(x); }

// row_newbcast:K (DPP ctrl 0x150+K): every lane of each 16-lane row receives
// src from lane K of that row. VALU pipe, no DS.
template<int K> __device__ __forceinline__ float bcast16(float x) {
    return __int_as_float(__builtin_amdgcn_update_dpp(
        __float_as_int(x), __float_as_int(x), 0x150 + K, 0xF, 0xF, false));
}

// v_pk_fma_f32 variants. All vector sources must be 64-bit pairs.
// LL: both result halves use src1.lo. HH: both use src1.hi.
#define PK_FMA_LL(acc, w, x) asm("v_pk_fma_f32 %0, %1, %2, %0 op_sel_hi:[1,0,1]" \
                                 : "+v"(acc) : "v"(w), "v"(x))
#define PK_FMA_HH(acc, w, x) asm("v_pk_fma_f32 %0, %1, %2, %0 op_sel:[0,1,0] op_sel_hi:[1,1,1]" \
                                 : "+v"(acc) : "v"(w), "v"(x))
#define PK_ADD(d, a, b)      asm("v_pk_add_f32 %0, %1, %2" : "=v"(d) : "v"(a), "v"(b))

struct LW {
    v2f wx[INSZ];   // {rowA, rowB} coefficients per input, scale folded
    v2f wh[HID];
    v2f bias;
    float mA, oA;   // gateA affine: sigmoid (1,0) on low half, tanh (2,-1) on high
};

// One LSTM step. Low half (lanes <32) computes (i,f) rows, high half (g,o).
// v_permlane32_swap with equal operands x returns:
//   ret[0] = x's LOW-half value on all 64 lanes,
//   ret[1] = x's HIGH-half value on all 64 lanes.   (verified by R9 absmax)
__device__ __forceinline__ void lstm_step(const float4& X0, const float4& X1,
        const LW& W, float& hst, float& cst) {
    v2f ae = W.bias, ao = {0.f, 0.f};
    const v2f xp0 = {X0.x, X0.y}, xp1 = {X0.z, X0.w};
    const v2f xp2 = {X1.x, X1.y}, xp3 = {X1.z, X1.w};
    PK_FMA_LL(ae, W.wx[0], xp0); PK_FMA_HH(ao, W.wx[1], xp0);
    PK_FMA_LL(ae, W.wx[2], xp1); PK_FMA_HH(ao, W.wx[3], xp1);
    PK_FMA_LL(ae, W.wx[4], xp2); PK_FMA_HH(ao, W.wx[5], xp2);
    PK_FMA_LL(ae, W.wx[6], xp3); PK_FMA_HH(ao, W.wx[7], xp3);
    // h-dot: 10 DPP broadcasts + 10 pk_fma; broadcast rides in hd.x (pair reg,
    // hi half never read under op_sel_hi:[1,0,1]) — R7-proven pattern.
    v2f hd = {0.f, 0.f};
#define HTERM(K, ACC) \
    hd.x = bcast16<K>(hst); \
    PK_FMA_LL(ACC, W.wh[K], hd)
    HTERM(0, ae); HTERM(1, ao);
    HTERM(2, ae); HTERM(3, ao);
    HTERM(4, ae); HTERM(5, ao);
    HTERM(6, ae); HTERM(7, ao);
    HTERM(8, ae); HTERM(9, ao);
#undef HTERM
    v2f a;
    PK_ADD(a, ae, ao);
    // weights pre-scaled (-log2e sigmoid rows, -2log2e tanh row):
    const float gA = fmaf(W.mA, rcp_(1.f + exp2_(a.x)), W.oA);  // i (low) / g (high)
    const float gB = rcp_(1.f + exp2_(a.y));                    // f (low) / o (high)
    const auto s1 = __builtin_amdgcn_permlane32_swap(
        __float_as_uint(gA), __float_as_uint(gA), false, false);
    const auto s2 = __builtin_amdgcn_permlane32_swap(
        __float_as_uint(gB), __float_as_uint(gB), false, false);
    const float iv = __uint_as_float(s1[0]);  // low half computed i
    const float gv = __uint_as_float(s1[1]);  // high half computed g
    const float fv = __uint_as_float(s2[0]);  // low half computed f
    const float ov = __uint_as_float(s2[1]);  // high half computed o
    cst = fmaf(fv, cst, iv * gv);
    const float th = fmaf(2.f, rcp_(1.f + exp2_(cst * (-2.f * LOG2E))), -1.f);
    hst = ov * th;
}

// One global_load_lds dwordx4: lane l's 16 B -> ldsbase + l*16 (wave-uniform
// base, linear lane layout). Consumers read through LDS (memory), so
// "memory"-clobbered counted waits order them correctly (R7-proven).
__device__ __forceinline__ void stage_tile(const float* gsrc_lane, float* ldsbase) {
    __builtin_amdgcn_global_load_lds(
        (const __attribute__((address_space(1))) void*)(uintptr_t)gsrc_lane,
        (__attribute__((address_space(3))) void*)(uint32_t)(uintptr_t)ldsbase,
        16, 0, 0);
}

template<int VM>
__device__ __forceinline__ void consume_tile(const float (&xb)[TSTEPS][2][INSZ],
        int c, const LW& W, float& hst, float& cst) {
    __builtin_amdgcn_sched_barrier(0);
    asm volatile("s_waitcnt vmcnt(%0)" :: "i"(VM) : "memory");
    __builtin_amdgcn_sched_barrier(0);
#pragma unroll
    for (int s = 0; s < TSTEPS; ++s) {
        const float4 xlo = *(const float4*)&xb[s][c][0];
        const float4 xhi = *(const float4*)&xb[s][c][4];
        lstm_step(xlo, xhi, W, hst, cst);
    }
}

// 32 lanes per chain (split across the permlane32 boundary), 2 chains per
// wave, 2048 waves = 2 waves/SIMD. Chain c owns lanes {c*16..c*16+15} (i,f
// rows) and {32+c*16..32+c*16+15} (g,o rows). Both halves maintain c,h
// redundantly (identical values). Zero DS ops in the recurrence.
__global__ void __attribute__((amdgpu_flat_work_group_size(64, 64)))
                __attribute__((amdgpu_waves_per_eu(2, 2)))
lstm_fused(
    const float* __restrict__ x,
    const float* __restrict__ h0,
    const float* __restrict__ c0,
    const float* __restrict__ Wih,
    const float* __restrict__ Whh,
    const float* __restrict__ bih,
    const float* __restrict__ bhh,
    const float* __restrict__ Wfc,
    const float* __restrict__ bfc,
    float* __restrict__ out)
{
    __shared__ float xbuf[NBUF][TSTEPS][2][INSZ];   // 4 KB

    const int lane = threadIdx.x;
    const int j16  = lane & 15;
    const int c    = (lane >> 4) & 1;               // chain within wave
    const int h2   = lane >> 5;                     // 0: (i,f) rows, 1: (g,o)
    const int n    = ((int)blockIdx.x << 1) + c;
    const int j    = (j16 < HID) ? j16 : 0;         // padding lanes mirror unit 0

    const int rowA = h2 ? 2 * HID + j : j;          // i or g
    const int rowB = rowA + HID;                    // f or o
    const float sA = h2 ? -2.f * LOG2E : -LOG2E;
    const float sB = -LOG2E;

    LW W;
#pragma unroll
    for (int i = 0; i < INSZ; ++i)
        W.wx[i] = (v2f){Wih[rowA * INSZ + i] * sA, Wih[rowB * INSZ + i] * sB};
#pragma unroll
    for (int k = 0; k < HID; ++k)
        W.wh[k] = (v2f){Whh[rowA * HID + k] * sA, Whh[rowB * HID + k] * sB};
    W.bias = (v2f){(bih[rowA] + bhh[rowA]) * sA, (bih[rowB] + bhh[rowB]) * sB};
    W.mA = h2 ? 2.f : 1.f;
    W.oA = h2 ? -1.f : 0.f;

    float cst = c0[n * HID + j];
    float hst = h0[n * HID + j];

    // Staging source: lane l covers (ts = l>>2, chain = (l>>1)&1, half = l&1)
    // -> LDS byte l*16 matches xbuf[..][ts][ch][half*4..+3].
    const int ts = lane >> 2, ch = (lane >> 1) & 1, hf = lane & 1;
    const float* gl = x + (size_t)ts * XS
                        + (size_t)((((int)blockIdx.x << 1) + ch) * INSZ + hf * 4);

    asm volatile("" ::: "memory");
#pragma unroll
    for (int b = 0; b < NBUF; ++b) {
        stage_tile(gl, &xbuf[b][0][0][0]);
        asm volatile("" ::: "memory");
        gl += (size_t)TSTEPS * XS;
    }

    // Main: counted vmcnt(3) completes exactly the oldest (this tile's) DMA;
    // lgkmcnt(0) ensures the buffer's ds_reads retired before its rewrite.
    for (int tile = 0; tile < NTILES - NBUF; ++tile) {
        const int b = tile & (NBUF - 1);
        consume_tile<3>(xbuf[b], c, W, hst, cst);
        asm volatile("s_waitcnt lgkmcnt(0)" ::: "memory");
        stage_tile(gl, &xbuf[b][0][0][0]);
        asm volatile("" ::: "memory");
        gl += (size_t)TSTEPS * XS;
    }
    // Drain: descending counted waits, no reissue.
    consume_tile<3>(xbuf[0], c, W, hst, cst);
    consume_tile<2>(xbuf[1], c, W, hst, cst);
    consume_tile<1>(xbuf[2], c, W, hst, cst);
    consume_tile<0>(xbuf[3], c, W, hst, cst);

    // Epilogue: collect h via DPP (each 16-row holds its chain's full h).
    float hv[HID];
    hv[0] = bcast16<0>(hst); hv[1] = bcast16<1>(hst);
    hv[2] = bcast16<2>(hst); hv[3] = bcast16<3>(hst);
    hv[4] = bcast16<4>(hst); hv[5] = bcast16<5>(hst);
    hv[6] = bcast16<6>(hst); hv[7] = bcast16<7>(hst);
    hv[8] = bcast16<8>(hst); hv[9] = bcast16<9>(hst);

    if (h2 == 0 && j16 < INSZ) {
        float acc = bfc[j16];
#pragma unroll
        for (int k = 0; k < HID; ++k) acc += Wfc[j16 * HID + k] * hv[k];
        out[n * INSZ + j16] = acc;
    }
    if (h2 == 0 && j16 < HID) {
        out[NB * INSZ + n * HID + j16] = hst;
        out[NB * INSZ + NB * HID + n * HID + j16] = cst;
    }
}

extern "C" void kernel_launch(void* const* d_in, const int* in_sizes, int n_in,
                              void* d_out, int out_size, void* d_ws, size_t ws_size,
                              hipStream_t stream) {
    const float* x   = (const float*)d_in[0];
    const float* h0  = (const float*)d_in[1];
    const float* c0  = (const float*)d_in[2];
    const float* Wih = (const float*)d_in[3];
    const float* Whh = (const float*)d_in[4];
    const float* bih = (const float*)d_in[5];
    const float* bhh = (const float*)d_in[6];
    const float* Wfc = (const float*)d_in[7];
    const float* bfc = (const float*)d_in[8];
    float* out = (float*)d_out;

    lstm_fused<<<NB / 2, 64, 0, stream>>>(x, h0, c0, Wih, Whh, bih, bhh, Wfc, bfc, out);
}

// Round 11
// 489.993 us; speedup vs baseline: 1.0585x; 1.0585x over previous
//
#include <hip/hip_runtime.h>
#include <stdint.h>

#define TL  2048
#define NB  4096
#define INSZ 8
#define HID 10
#define LOG2E 1.4426950408889634f
#define XS (NB * INSZ)            // floats per timestep slab
#define TSTEPS 8                  // timesteps per staged tile (1 KB DMA)
#define NBUF 4
#define NTILES (TL / TSTEPS)      // 256

typedef float v2f __attribute__((ext_vector_type(2)));

__device__ __forceinline__ float rcp_(float x)  { return __builtin_amdgcn_rcpf(x); }
__device__ __forceinline__ float exp2_(float x) { return __builtin_amdgcn_exp2f(x); }

// row_newbcast:K (DPP ctrl 0x150+K): every lane of each 16-lane row receives
// src from lane K of that row. VALU pipe, no DS.
template<int K> __device__ __forceinline__ float bcast16(float x) {
    return __int_as_float(__builtin_amdgcn_update_dpp(
        __float_as_int(x), __float_as_int(x), 0x150 + K, 0xF, 0xF, false));
}

// v_pk_fma_f32: acc.lo += w.lo * sel(x); acc.hi += w.hi * sel(x)
#define PK_FMA_LL(acc, w, x) asm("v_pk_fma_f32 %0, %1, %2, %0 op_sel_hi:[1,0,1]" \
                                 : "+v"(acc) : "v"(w), "v"(x))
#define PK_FMA_HH(acc, w, x) asm("v_pk_fma_f32 %0, %1, %2, %0 op_sel:[0,1,0] op_sel_hi:[1,1,1]" \
                                 : "+v"(acc) : "v"(w), "v"(x))
#define PK_ADD(d, a, b)      asm("v_pk_add_f32 %0, %1, %2" : "=v"(d) : "v"(a), "v"(b))

// Opaque pin: unknown definition -> compiler cannot rematerialize (reload+mul)
// the value inside the loop; it must stay register-resident. (R7's VGPR=68
// proved the scaled weights were being rematerialized per step.)
#define PIN(v) asm("" : "+v"(v))

struct LWeights {
    v2f wx01[INSZ], wx23[INSZ];   // (i,f) and (g,o) gate pairs, scale folded
    v2f wh01[HID],  wh23[HID];
    v2f b01, b23;
};

__device__ __forceinline__ void lstm_step(const float4& X0, const float4& X1,
        const LWeights& W, float& hst, float& cst) {
    v2f a01e = W.b01, a23e = W.b23;
    v2f a01o = {0.f, 0.f}, a23o = {0.f, 0.f};
    const v2f xp0 = {X0.x, X0.y}, xp1 = {X0.z, X0.w};
    const v2f xp2 = {X1.x, X1.y}, xp3 = {X1.z, X1.w};
    // x-dot: 16 pk_fma, even i -> e-bank (LL), odd i -> o-bank (HH)
    PK_FMA_LL(a01e, W.wx01[0], xp0); PK_FMA_LL(a23e, W.wx23[0], xp0);
    PK_FMA_HH(a01o, W.wx01[1], xp0); PK_FMA_HH(a23o, W.wx23[1], xp0);
    PK_FMA_LL(a01e, W.wx01[2], xp1); PK_FMA_LL(a23e, W.wx23[2], xp1);
    PK_FMA_HH(a01o, W.wx01[3], xp1); PK_FMA_HH(a23o, W.wx23[3], xp1);
    PK_FMA_LL(a01e, W.wx01[4], xp2); PK_FMA_LL(a23e, W.wx23[4], xp2);
    PK_FMA_HH(a01o, W.wx01[5], xp2); PK_FMA_HH(a23o, W.wx23[5], xp2);
    PK_FMA_LL(a01e, W.wx01[6], xp3); PK_FMA_LL(a23e, W.wx23[6], xp3);
    PK_FMA_HH(a01o, W.wx01[7], xp3); PK_FMA_HH(a23o, W.wx23[7], xp3);
    // h-dot: 10 bcast + 20 pk_fma (hd.y never read: LL selects lo)
    v2f hd = {0.f, 0.f};
#define HTERM(K, A01, A23) \
    hd.x = bcast16<K>(hst); \
    PK_FMA_LL(A01, W.wh01[K], hd); PK_FMA_LL(A23, W.wh23[K], hd)
    HTERM(0, a01e, a23e); HTERM(1, a01o, a23o);
    HTERM(2, a01e, a23e); HTERM(3, a01o, a23o);
    HTERM(4, a01e, a23e); HTERM(5, a01o, a23o);
    HTERM(6, a01e, a23e); HTERM(7, a01o, a23o);
    HTERM(8, a01e, a23e); HTERM(9, a01o, a23o);
#undef HTERM
    v2f a01, a23;
    PK_ADD(a01, a01e, a01o);
    PK_ADD(a23, a23e, a23o);
    // Activations via batched reciprocal: ONE rcp serves all 4 gate sigmoids.
    // Weights pre-scaled by -log2e (i,f,o) / -2log2e (g), so d = 1+exp2(a).
    // Overflow-safe: |a_scaled| <= ~25 each -> product <= ~2^61 << 2^127.
    const float e0 = exp2_(a01.x);
    const float e1 = exp2_(a01.y);
    const float e2 = exp2_(a23.x);
    const float e3 = exp2_(a23.y);
    const float d0 = 1.f + e0, d1 = 1.f + e1, d2 = 1.f + e2, d3 = 1.f + e3;
    const float p01 = d0 * d1, p23 = d2 * d3;
    const float r   = rcp_(p01 * p23);
    const float r01 = r * p23, r23 = r * p01;
    const float ig = r01 * d1;                    // 1/d0 = sigmoid(i)
    const float fg = r01 * d0;                    // 1/d1 = sigmoid(f)
    const float gg = fmaf(2.f, r23 * d3, -1.f);   // 2/d2-1 = tanh(g)
    const float og = r23 * d2;                    // 1/d3 = sigmoid(o)
    cst = fmaf(fg, cst, ig * gg);
    const float eth = exp2_(cst * (-2.f * LOG2E));
    const float th  = fmaf(2.f, rcp_(1.f + eth), -1.f);
    hst = og * th;
}

// One global_load_lds dwordx4: lane l's 16 B -> ldsbase + l*16 (wave-uniform
// base, linear lane layout). Consumers read through LDS (memory), so
// "memory"-clobbered counted waits order them correctly (R7-proven).
__device__ __forceinline__ void stage_tile(const float* gsrc_lane, float* ldsbase) {
    __builtin_amdgcn_global_load_lds(
        (const __attribute__((address_space(1))) void*)(uintptr_t)gsrc_lane,
        (__attribute__((address_space(3))) void*)(uint32_t)(uintptr_t)ldsbase,
        16, 0, 0);
}

template<int VM>
__device__ __forceinline__ void consume_tile(const float (&xb)[TSTEPS][4][INSZ],
        int grp, const LWeights& W, float& hst, float& cst) {
    __builtin_amdgcn_sched_barrier(0);
    asm volatile("s_waitcnt vmcnt(%0)" :: "i"(VM) : "memory");
    __builtin_amdgcn_sched_barrier(0);
#pragma unroll
    for (int s = 0; s < TSTEPS; ++s) {
        const float4 xlo = *(const float4*)&xb[s][grp][0];
        const float4 xhi = *(const float4*)&xb[s][grp][4];
        lstm_step(xlo, xhi, W, hst, cst);
    }
}

// 16 lanes per chain, 4 chains per wave, 1024 waves = 1 wave/SIMD.
// Lane j16<10 owns hidden unit j: gate rows {j,10+j,20+j,30+j}.
// h exchanged via DPP row_newbcast. x staged via 4-deep LDS pipeline.
__global__ void __attribute__((amdgpu_flat_work_group_size(64, 64)))
                __attribute__((amdgpu_waves_per_eu(1)))
lstm_fused(
    const float* __restrict__ x,
    const float* __restrict__ h0,
    const float* __restrict__ c0,
    const float* __restrict__ Wih,
    const float* __restrict__ Whh,
    const float* __restrict__ bih,
    const float* __restrict__ bhh,
    const float* __restrict__ Wfc,
    const float* __restrict__ bfc,
    float* __restrict__ out)
{
    __shared__ float xbuf[NBUF][TSTEPS][4][INSZ];   // 4 KB

    const int lane = threadIdx.x;
    const int j16  = lane & 15;
    const int grp  = lane >> 4;
    const int n    = ((int)blockIdx.x << 2) + grp;
    const int j    = (j16 < HID) ? j16 : 0;   // clamp padding lanes
    const int src  = lane & 48;               // 16-lane group base

    const int ri = j, rf = HID + j, rg = 2 * HID + j, ro = 3 * HID + j;
    const float si = -LOG2E, sg = -2.f * LOG2E;

    LWeights W;
#pragma unroll
    for (int i = 0; i < INSZ; ++i) {
        W.wx01[i] = (v2f){Wih[ri * INSZ + i] * si, Wih[rf * INSZ + i] * si};
        W.wx23[i] = (v2f){Wih[rg * INSZ + i] * sg, Wih[ro * INSZ + i] * si};
    }
#pragma unroll
    for (int k = 0; k < HID; ++k) {
        W.wh01[k] = (v2f){Whh[ri * HID + k] * si, Whh[rf * HID + k] * si};
        W.wh23[k] = (v2f){Whh[rg * HID + k] * sg, Whh[ro * HID + k] * si};
    }
    W.b01 = (v2f){(bih[ri] + bhh[ri]) * si, (bih[rf] + bhh[rf]) * si};
    W.b23 = (v2f){(bih[rg] + bhh[rg]) * sg, (bih[ro] + bhh[ro]) * si};

    // Pin all 38 weight pairs: forces register residency for the whole loop.
#pragma unroll
    for (int i = 0; i < INSZ; ++i) { PIN(W.wx01[i]); PIN(W.wx23[i]); }
#pragma unroll
    for (int k = 0; k < HID; ++k) { PIN(W.wh01[k]); PIN(W.wh23[k]); }
    PIN(W.b01); PIN(W.b23);

    float cst = c0[n * HID + j];
    float hst = h0[n * HID + j];

    // Per-lane staging source: lane l covers (ts = l>>3, chain = (l>>1)&3,
    // half = l&1) -> LDS byte l*16 matches xbuf[..][ts][chain][half*4..+3].
    const int ts = lane >> 3, ch = (lane >> 1) & 3, hf = lane & 1;
    const float* gl = x + (size_t)ts * XS
                        + (size_t)((((int)blockIdx.x << 2) + ch) * INSZ + hf * 4);

    asm volatile("" ::: "memory");
#pragma unroll
    for (int b = 0; b < NBUF; ++b) {
        stage_tile(gl, &xbuf[b][0][0][0]);
        asm volatile("" ::: "memory");
        gl += (size_t)TSTEPS * XS;
    }

    // Main: counted vmcnt(3) completes exactly the oldest (this tile's) DMA;
    // lgkmcnt(0) ensures the buffer's ds_reads retired before its rewrite.
    for (int tile = 0; tile < NTILES - NBUF; ++tile) {
        const int b = tile & (NBUF - 1);
        consume_tile<3>(xbuf[b], grp, W, hst, cst);
        asm volatile("s_waitcnt lgkmcnt(0)" ::: "memory");
        stage_tile(gl, &xbuf[b][0][0][0]);
        asm volatile("" ::: "memory");
        gl += (size_t)TSTEPS * XS;
    }
    // Drain: descending counted waits, no reissue.
    consume_tile<3>(xbuf[0], grp, W, hst, cst);
    consume_tile<2>(xbuf[1], grp, W, hst, cst);
    consume_tile<1>(xbuf[2], grp, W, hst, cst);
    consume_tile<0>(xbuf[3], grp, W, hst, cst);

    // epilogue (one-time, DS shuffles fine here): y = h @ W_fc.T + b_fc; dump h, c
    float hv[HID];
#pragma unroll
    for (int k = 0; k < HID; ++k) hv[k] = __shfl(hst, src + k, 64);

    if (j16 < INSZ) {
        float acc = bfc[j16];
#pragma unroll
        for (int k = 0; k < HID; ++k) acc += Wfc[j16 * HID + k] * hv[k];
        out[n * INSZ + j16] = acc;
    }
    if (j16 < HID) {
        out[NB * INSZ + n * HID + j16] = hst;
        out[NB * INSZ + NB * HID + n * HID + j16] = cst;
    }
}

extern "C" void kernel_launch(void* const* d_in, const int* in_sizes, int n_in,
                              void* d_out, int out_size, void* d_ws, size_t ws_size,
                              hipStream_t stream) {
    const float* x   = (const float*)d_in[0];
    const float* h0  = (const float*)d_in[1];
    const float* c0  = (const float*)d_in[2];
    const float* Wih = (const float*)d_in[3];
    const float* Whh = (const float*)d_in[4];
    const float* bih = (const float*)d_in[5];
    const float* bhh = (const float*)d_in[6];
    const float* Wfc = (const float*)d_in[7];
    const float* bfc = (const float*)d_in[8];
    float* out = (float*)d_out;

    lstm_fused<<<NB / 4, 64, 0, stream>>>(x, h0, c0, Wih, Whh, bih, bhh, Wfc, bfc, out);
}